// Round 8
// baseline (101.751 us; speedup 1.0000x reference)
//
#include <hip/hip_runtime.h>
#include <hip/hip_bf16.h>

typedef __hip_bfloat16 bf16;
typedef __attribute__((ext_vector_type(8))) short bf16x8;   // 8 bf16 = 4 VGPR
typedef __attribute__((ext_vector_type(4))) float f32x4;

#define MFMA16(a, b, c) __builtin_amdgcn_mfma_f32_16x16x32_bf16((a), (b), (c), 0, 0, 0)

// ---- constants ----
// B=2, S=2048, D=768, HD=64, NH=12, NKV=4, GROUPS=3, WINDOW=384, theta=1e4, eps=1e-6
// I/O fp32; bf16 intermediates in ws; V stored transposed [b][kv][d][s].

__device__ __forceinline__ void st4bf(bf16* p, float4 v) {
    bf16 t[4];
    t[0] = __float2bfloat16(v.x); t[1] = __float2bfloat16(v.y);
    t[2] = __float2bfloat16(v.z); t[3] = __float2bfloat16(v.w);
    *reinterpret_cast<uint2*>(p) = *reinterpret_cast<const uint2*>(t);
}

// ============ Kernel 0: fp32->bf16 conversion of hs + weights, and RoPE table ======
__global__ __launch_bounds__(256) void k_prep(
    const float* __restrict__ hs, const float* __restrict__ qw,
    const float* __restrict__ kw, const float* __restrict__ vw,
    const float* __restrict__ ow,
    bf16* __restrict__ hsb, bf16* __restrict__ qwb, bf16* __restrict__ kwb,
    bf16* __restrict__ vwb, bf16* __restrict__ owb, float2* __restrict__ tab)
{
    const int bid = blockIdx.x, tid = threadIdx.x;
    const float* src; bf16* dst; int rel;
    if (bid < 3072)      { src = hs; dst = hsb; rel = bid; }
    else if (bid < 3648) { src = qw; dst = qwb; rel = bid - 3072; }
    else if (bid < 3840) { src = kw; dst = kwb; rel = bid - 3648; }
    else if (bid < 4032) { src = vw; dst = vwb; rel = bid - 3840; }
    else if (bid < 4608) { src = ow; dst = owb; rel = bid - 4032; }
    else {
        int i = (bid - 4608) * 256 + tid;          // 65536 entries
        int f = i & 31;
        float ang = (float)(i >> 5) * expf(-(float)f * 0.28782313662425572f);  // ln(1e4)/32
        float sn, cs; sincosf(ang, &sn, &cs);
        tab[i] = make_float2(cs, sn);
        return;
    }
    int i = (rel * 256 + tid) * 4;
    float4 v = *reinterpret_cast<const float4*>(src + i);
    st4bf(dst + i, v);
}

// ================= Kernel 1: MFMA QKV GEMM + RMSNorm + RoPE (128x128, 64x64 waves) =
__global__ __launch_bounds__(256) void k_qkv(
    const bf16* __restrict__ hsb, const bf16* __restrict__ qwb,
    const bf16* __restrict__ kwb, const bf16* __restrict__ vwb,
    const float* __restrict__ qln, const float* __restrict__ kln,
    const float2* __restrict__ tab,
    bf16* __restrict__ qo, bf16* __restrict__ ko, bf16* __restrict__ vto)
{
    __shared__ bf16 As[2][128 * 72];
    __shared__ bf16 Bs[2][128 * 72];
    const int tid = threadIdx.x;
    const int w = tid >> 6, l = tid & 63;
    const int lm = l & 15, lg = l >> 4;
    const int wr = w >> 1, wc = w & 1;
    const int m0 = blockIdx.x * 128;
    const int nblk = blockIdx.y;

    const bf16* wsrc; int kind, head;
    if (nblk < 6)      { wsrc = qwb + (size_t)nblk * 128 * 768;       kind = 0; head = nblk * 2 + wc; }
    else if (nblk < 8) { wsrc = kwb + (size_t)(nblk - 6) * 128 * 768; kind = 1; head = (nblk - 6) * 2 + wc; }
    else               { wsrc = vwb + (size_t)(nblk - 8) * 128 * 768; kind = 2; head = (nblk - 8) * 2 + wc; }

    const int sr = tid >> 1, scb = (tid & 1) * 8;
    const bf16* aptr = hsb  + (size_t)(m0 + sr) * 768 + scb;
    const bf16* bptr = wsrc + (size_t)sr * 768 + scb;

    bf16x8 ra[4], rb[4];
    #pragma unroll
    for (int j = 0; j < 4; ++j) {
        ra[j] = *(const bf16x8*)(aptr + j * 16);
        rb[j] = *(const bf16x8*)(bptr + j * 16);
    }
    #pragma unroll
    for (int j = 0; j < 4; ++j) {
        *(bf16x8*)(&As[0][sr * 72 + scb + j * 16]) = ra[j];
        *(bf16x8*)(&Bs[0][sr * 72 + scb + j * 16]) = rb[j];
    }
    __syncthreads();

    f32x4 acc[4][4] = {};
    for (int t = 0; t < 12; ++t) {
        const int p = t & 1;
        if (t < 11) {
            const int off = (t + 1) * 64;
            #pragma unroll
            for (int j = 0; j < 4; ++j) {
                ra[j] = *(const bf16x8*)(aptr + off + j * 16);
                rb[j] = *(const bf16x8*)(bptr + off + j * 16);
            }
        }
        #pragma unroll
        for (int kk = 0; kk < 2; ++kk) {
            bf16x8 af[4], bfv[4];
            #pragma unroll
            for (int mf = 0; mf < 4; ++mf)
                af[mf] = *(const bf16x8*)(&As[p][(wr * 64 + mf * 16 + lm) * 72 + kk * 32 + lg * 8]);
            #pragma unroll
            for (int ct = 0; ct < 4; ++ct)
                bfv[ct] = *(const bf16x8*)(&Bs[p][(wc * 64 + ct * 16 + lm) * 72 + kk * 32 + lg * 8]);
            #pragma unroll
            for (int mf = 0; mf < 4; ++mf)
                #pragma unroll
                for (int ct = 0; ct < 4; ++ct)
                    acc[mf][ct] = MFMA16(af[mf], bfv[ct], acc[mf][ct]);
        }
        if (t < 11) {
            __syncthreads();
            #pragma unroll
            for (int j = 0; j < 4; ++j) {
                *(bf16x8*)(&As[p ^ 1][sr * 72 + scb + j * 16]) = ra[j];
                *(bf16x8*)(&Bs[p ^ 1][sr * 72 + scb + j * 16]) = rb[j];
            }
            __syncthreads();
        }
    }

    const int b  = m0 >> 11;
    const int s0 = m0 & 2047;

    if (kind == 2) {  // V: write TRANSPOSED [b][kv][d][s]
        bf16* base = vto + (size_t)(b * 4 + head) * 64 * 2048;
        #pragma unroll
        for (int mf = 0; mf < 4; ++mf)
            #pragma unroll
            for (int r = 0; r < 4; ++r) {
                const int s = s0 + wr * 64 + mf * 16 + lg * 4 + r;
                #pragma unroll
                for (int ct = 0; ct < 4; ++ct)
                    base[(size_t)(ct * 16 + lm) * 2048 + s] = __float2bfloat16(acc[mf][ct][r]);
            }
        return;
    }

    const float* ln = (kind == 0) ? qln : kln;
    float lw[4];
    #pragma unroll
    for (int ct = 0; ct < 4; ++ct) lw[ct] = ln[ct * 16 + lm];

    bf16* base = (kind == 0) ? qo + ((size_t)(b * 12 + head) * 2048 + s0) * 64
                             : ko + ((size_t)(b * 4  + head) * 2048 + s0) * 64;
    #pragma unroll
    for (int mf = 0; mf < 4; ++mf)
        #pragma unroll
        for (int r = 0; r < 4; ++r) {
            float n0 = acc[mf][0][r], n1 = acc[mf][1][r], n2 = acc[mf][2][r], n3 = acc[mf][3][r];
            float ss = n0 * n0 + n1 * n1 + n2 * n2 + n3 * n3;
            ss += __shfl_xor(ss, 1);
            ss += __shfl_xor(ss, 2);
            ss += __shfl_xor(ss, 4);
            ss += __shfl_xor(ss, 8);
            float rms = rsqrtf(ss * (1.0f / 64.0f) + 1e-6f);
            n0 *= rms * lw[0]; n1 *= rms * lw[1]; n2 *= rms * lw[2]; n3 *= rms * lw[3];
            const int row = wr * 64 + mf * 16 + lg * 4 + r;
            const float2* tp = tab + (size_t)(s0 + row) * 32;
            float2 t0 = tp[lm], t1 = tp[lm + 16];
            bf16* dst = base + (size_t)row * 64;
            dst[lm]      = __float2bfloat16(n0 * t0.x - n2 * t0.y);
            dst[lm + 16] = __float2bfloat16(n1 * t1.x - n3 * t1.y);
            dst[lm + 32] = __float2bfloat16(n2 * t0.x + n0 * t0.y);
            dst[lm + 48] = __float2bfloat16(n3 * t1.x + n1 * t1.y);
        }
}

// ================= Kernel 2: MFMA attention, NO K/V staging (L1/L2-direct) ========
// grid (32 q-tiles, 12 heads, 2 batch); 4 waves/block; barrier-free main loop.
__global__ __launch_bounds__(256) void k_attn(
    const bf16* __restrict__ qi, const bf16* __restrict__ ki,
    const bf16* __restrict__ vti, bf16* __restrict__ ao)
{
    __shared__ bf16 Ps[64 * 72];      // per-wave-private rows only
    const int tid = threadIdx.x;
    const int w = tid >> 6, l = tid & 63;
    const int lm = l & 15, lg = l >> 4;
    const int qb = blockIdx.x, h = blockIdx.y, b = blockIdx.z;
    const int kv = h / 3;
    const int q0 = qb * 64;
    const float SCL2 = 0.18033688011117042f;   // 0.125 * log2(e)

    const bf16* qbase = qi + ((size_t)((b * 12 + h) * 2048 + q0 + w * 16 + lm)) * 64 + lg * 8;
    bf16x8 qf0 = *(const bf16x8*)(qbase);
    bf16x8 qf1 = *(const bf16x8*)(qbase + 32);

    f32x4 oacc[4] = {};
    float m_[4], l_[4];
    #pragma unroll
    for (int r = 0; r < 4; ++r) { m_[r] = -INFINITY; l_[r] = 0.f; }

    // direct-load bases: K [key][d] rows of 128B; V^T [d][key] rows of 4KB
    const bf16* krow = ki  + (size_t)(b * 4 + kv) * 2048 * 64 + (size_t)lm * 64 + lg * 8;
    const bf16* vrow = vti + (size_t)(b * 4 + kv) * 64 * 2048 + (size_t)lm * 2048 + lg * 8;

    const int kb_lo = (qb > 6) ? (qb - 6) : 0;
    for (int kb = kb_lo; kb <= qb; ++kb) {
        const int k0 = kb * 64;

        // S = Q K^T straight from cache: lanes (lm fixed, lg=0..3) cover one 64B line
        f32x4 sacc[4];
        #pragma unroll
        for (int kt = 0; kt < 4; ++kt) {
            const bf16* kp = krow + (size_t)(k0 + kt * 16) * 64;
            bf16x8 kf0 = *(const bf16x8*)(kp);
            bf16x8 kf1 = *(const bf16x8*)(kp + 32);
            f32x4 z = {0.f, 0.f, 0.f, 0.f};
            z = MFMA16(qf0, kf0, z);
            sacc[kt] = MFMA16(qf1, kf1, z);
        }

        float pmax[4] = {-INFINITY, -INFINITY, -INFINITY, -INFINITY};
        #pragma unroll
        for (int kt = 0; kt < 4; ++kt)
            #pragma unroll
            for (int r = 0; r < 4; ++r) {
                int kgl = k0 + kt * 16 + lm;
                int qgl = q0 + w * 16 + lg * 4 + r;
                bool ok = (kgl <= qgl) && (kgl > qgl - 384);
                float s = ok ? sacc[kt][r] * SCL2 : -INFINITY;
                sacc[kt][r] = s;
                pmax[r] = fmaxf(pmax[r], s);
            }
        #pragma unroll
        for (int r = 0; r < 4; ++r) {
            float t = pmax[r];
            t = fmaxf(t, __shfl_xor(t, 1));
            t = fmaxf(t, __shfl_xor(t, 2));
            t = fmaxf(t, __shfl_xor(t, 4));
            t = fmaxf(t, __shfl_xor(t, 8));
            pmax[r] = t;
        }

        #pragma unroll
        for (int r = 0; r < 4; ++r) {
            float mnew = fmaxf(m_[r], pmax[r]);
            float scale, rs = 0.f, pv[4];
            if (mnew > -INFINITY) {
                scale = exp2f(m_[r] - mnew);
                #pragma unroll
                for (int kt = 0; kt < 4; ++kt) { pv[kt] = exp2f(sacc[kt][r] - mnew); rs += pv[kt]; }
            } else {
                scale = 1.f;
                #pragma unroll
                for (int kt = 0; kt < 4; ++kt) pv[kt] = 0.f;
            }
            m_[r] = mnew;
            rs += __shfl_xor(rs, 1);
            rs += __shfl_xor(rs, 2);
            rs += __shfl_xor(rs, 4);
            rs += __shfl_xor(rs, 8);
            l_[r] = l_[r] * scale + rs;
            #pragma unroll
            for (int dt = 0; dt < 4; ++dt) oacc[dt][r] *= scale;
            #pragma unroll
            for (int kt = 0; kt < 4; ++kt)
                Ps[(w * 16 + lg * 4 + r) * 72 + kt * 16 + lm] = __float2bfloat16(pv[kt]);
        }

        bf16x8 pf0 = *(const bf16x8*)(&Ps[(w * 16 + lm) * 72 + lg * 8]);
        bf16x8 pf1 = *(const bf16x8*)(&Ps[(w * 16 + lm) * 72 + 32 + lg * 8]);
        #pragma unroll
        for (int dt = 0; dt < 4; ++dt) {
            const bf16* vp = vrow + (size_t)(dt * 16) * 2048 + k0;
            bf16x8 vf0 = *(const bf16x8*)(vp);
            bf16x8 vf1 = *(const bf16x8*)(vp + 32);
            oacc[dt] = MFMA16(pf0, vf0, oacc[dt]);
            oacc[dt] = MFMA16(pf1, vf1, oacc[dt]);
        }
    }

    #pragma unroll
    for (int r = 0; r < 4; ++r) {
        float inv = 1.f / l_[r];
        bf16* dst = ao + ((size_t)(b * 2048 + q0 + w * 16 + lg * 4 + r)) * 768 + h * 64;
        #pragma unroll
        for (int dt = 0; dt < 4; ++dt)
            dst[dt * 16 + lm] = __float2bfloat16(oacc[dt][r] * inv);
    }
}

// ================= Kernel 3: LDS-free MFMA output projection ======================
// grid (32 m, 6 n), 4 waves 2x2; operands straight from L1/L2; zero barriers.
__global__ __launch_bounds__(256) void k_oproj(
    const bf16* __restrict__ A, const bf16* __restrict__ W, float* __restrict__ out)
{
    const int tid = threadIdx.x;
    const int w = tid >> 6, l = tid & 63;
    const int lm = l & 15, lg = l >> 4;
    const int wr = w >> 1, wc = w & 1;
    const int m0 = blockIdx.x * 128, n0 = blockIdx.y * 128;

    const bf16* arow[4];
    const bf16* brow[4];
    #pragma unroll
    for (int i = 0; i < 4; ++i) {
        arow[i] = A + (size_t)(m0 + wr * 64 + i * 16 + lm) * 768 + lg * 8;
        brow[i] = W + (size_t)(n0 + wc * 64 + i * 16 + lm) * 768 + lg * 8;
    }

    f32x4 acc[4][4] = {};
    for (int t = 0; t < 12; ++t) {
        #pragma unroll
        for (int kk = 0; kk < 2; ++kk) {
            const int off = t * 64 + kk * 32;
            bf16x8 af[4], bfv[4];
            #pragma unroll
            for (int mf = 0; mf < 4; ++mf) af[mf]  = *(const bf16x8*)(arow[mf] + off);
            #pragma unroll
            for (int ct = 0; ct < 4; ++ct) bfv[ct] = *(const bf16x8*)(brow[ct] + off);
            #pragma unroll
            for (int mf = 0; mf < 4; ++mf)
                #pragma unroll
                for (int ct = 0; ct < 4; ++ct)
                    acc[mf][ct] = MFMA16(af[mf], bfv[ct], acc[mf][ct]);
        }
    }

    #pragma unroll
    for (int mf = 0; mf < 4; ++mf)
        #pragma unroll
        for (int r = 0; r < 4; ++r) {
            float* dst = out + (size_t)(m0 + wr * 64 + mf * 16 + lg * 4 + r) * 768 + n0 + wc * 64;
            #pragma unroll
            for (int ct = 0; ct < 4; ++ct)
                dst[ct * 16 + lm] = acc[mf][ct][r];
        }
}

extern "C" void kernel_launch(void* const* d_in, const int* in_sizes, int n_in,
                              void* d_out, int out_size, void* d_ws, size_t ws_size,
                              hipStream_t stream) {
    const float* hs  = (const float*)d_in[0];
    const float* qw  = (const float*)d_in[1];
    const float* kw  = (const float*)d_in[2];
    const float* vw  = (const float*)d_in[3];
    const float* ow  = (const float*)d_in[4];
    const float* qln = (const float*)d_in[5];
    const float* kln = (const float*)d_in[6];
    float* out = (float*)d_out;

    float2* tab  = (float2*)d_ws;
    bf16*   q_ws = (bf16*)(tab + 65536);
    bf16*   k_ws = q_ws + 3145728;
    bf16*   vt_ws= k_ws + 1048576;
    bf16*   x_ws = vt_ws + 1048576;    // hsb during k_qkv, attn output after
    bf16*   qwb  = x_ws + 3145728;
    bf16*   kwb  = qwb + 589824;
    bf16*   vwb  = kwb + 196608;
    bf16*   owb  = vwb + 196608;

    k_prep<<<dim3(4864), 256, 0, stream>>>(hs, qw, kw, vw, ow, x_ws, qwb, kwb, vwb, owb, tab);
    k_qkv<<<dim3(32, 10, 1), 256, 0, stream>>>(x_ws, qwb, kwb, vwb, qln, kln, tab, q_ws, k_ws, vt_ws);
    k_attn<<<dim3(32, 12, 2), 256, 0, stream>>>(q_ws, k_ws, vt_ws, x_ws);
    k_oproj<<<dim3(32, 6, 1), 256, 0, stream>>>(x_ws, owb, out);
}

// Round 9
// 86.519 us; speedup vs baseline: 1.1761x; 1.1761x over previous
//
#include <hip/hip_runtime.h>
#include <hip/hip_bf16.h>

typedef __hip_bfloat16 bf16;
typedef __attribute__((ext_vector_type(8))) short bf16x8;   // 8 bf16 = 4 VGPR
typedef __attribute__((ext_vector_type(4))) float f32x4;

#define MFMA16(a, b, c) __builtin_amdgcn_mfma_f32_16x16x32_bf16((a), (b), (c), 0, 0, 0)

// ---- constants ----
// B=2, S=2048, D=768, HD=64, NH=12, NKV=4, GROUPS=3, WINDOW=384, theta=1e4, eps=1e-6
// I/O fp32; bf16 intermediates in ws; V stored transposed [b][kv][d][s].
// Staging discipline (R8 lesson): reg-prefetch + SINGLE LDS buffer. Direct global->MFMA
// regressed 2x (latency-bound); dbuf LDS halves occupancy for no overlap gain.

__device__ __forceinline__ void st4bf(bf16* p, float4 v) {
    bf16 t[4];
    t[0] = __float2bfloat16(v.x); t[1] = __float2bfloat16(v.y);
    t[2] = __float2bfloat16(v.z); t[3] = __float2bfloat16(v.w);
    *reinterpret_cast<uint2*>(p) = *reinterpret_cast<const uint2*>(t);
}

// ============ Kernel 0: fp32->bf16 conversion of hs + weights, and RoPE table ======
__global__ __launch_bounds__(256) void k_prep(
    const float* __restrict__ hs, const float* __restrict__ qw,
    const float* __restrict__ kw, const float* __restrict__ vw,
    const float* __restrict__ ow,
    bf16* __restrict__ hsb, bf16* __restrict__ qwb, bf16* __restrict__ kwb,
    bf16* __restrict__ vwb, bf16* __restrict__ owb, float2* __restrict__ tab)
{
    const int bid = blockIdx.x, tid = threadIdx.x;
    const float* src; bf16* dst; int rel;
    if (bid < 3072)      { src = hs; dst = hsb; rel = bid; }
    else if (bid < 3648) { src = qw; dst = qwb; rel = bid - 3072; }
    else if (bid < 3840) { src = kw; dst = kwb; rel = bid - 3648; }
    else if (bid < 4032) { src = vw; dst = vwb; rel = bid - 3840; }
    else if (bid < 4608) { src = ow; dst = owb; rel = bid - 4032; }
    else {
        int i = (bid - 4608) * 256 + tid;          // 65536 entries
        int f = i & 31;
        float ang = (float)(i >> 5) * expf(-(float)f * 0.28782313662425572f);  // ln(1e4)/32
        float sn, cs; sincosf(ang, &sn, &cs);
        tab[i] = make_float2(cs, sn);
        return;
    }
    int i = (rel * 256 + tid) * 4;
    float4 v = *reinterpret_cast<const float4*>(src + i);
    st4bf(dst + i, v);
}

// ================= Kernel 1: MFMA QKV GEMM + RMSNorm + RoPE =================
// 128x128 block, 4 waves 2x2 (wave sub-tile 64x64), single LDS buffer + reg prefetch.
// grid (32 m-tiles, 10 n-blocks): nblk 0-5 q (head 2nblk+wc), 6-7 k, 8-9 v.
__global__ __launch_bounds__(256) void k_qkv(
    const bf16* __restrict__ hsb, const bf16* __restrict__ qwb,
    const bf16* __restrict__ kwb, const bf16* __restrict__ vwb,
    const float* __restrict__ qln, const float* __restrict__ kln,
    const float2* __restrict__ tab,
    bf16* __restrict__ qo, bf16* __restrict__ ko, bf16* __restrict__ vto)
{
    __shared__ bf16 As[128 * 72];
    __shared__ bf16 Bs[128 * 72];
    const int tid = threadIdx.x;
    const int w = tid >> 6, l = tid & 63;
    const int lm = l & 15, lg = l >> 4;
    const int wr = w >> 1, wc = w & 1;
    const int m0 = blockIdx.x * 128;
    const int nblk = blockIdx.y;

    const bf16* wsrc; int kind, head;
    if (nblk < 6)      { wsrc = qwb + (size_t)nblk * 128 * 768;       kind = 0; head = nblk * 2 + wc; }
    else if (nblk < 8) { wsrc = kwb + (size_t)(nblk - 6) * 128 * 768; kind = 1; head = (nblk - 6) * 2 + wc; }
    else               { wsrc = vwb + (size_t)(nblk - 8) * 128 * 768; kind = 2; head = (nblk - 8) * 2 + wc; }

    const int sr = tid >> 1, scb = (tid & 1) * 8;
    const bf16* aptr = hsb  + (size_t)(m0 + sr) * 768 + scb;
    const bf16* bptr = wsrc + (size_t)sr * 768 + scb;

    bf16x8 ra[4], rb[4];
    #pragma unroll
    for (int j = 0; j < 4; ++j) {
        ra[j] = *(const bf16x8*)(aptr + j * 16);
        rb[j] = *(const bf16x8*)(bptr + j * 16);
    }
    #pragma unroll
    for (int j = 0; j < 4; ++j) {
        *(bf16x8*)(&As[sr * 72 + scb + j * 16]) = ra[j];
        *(bf16x8*)(&Bs[sr * 72 + scb + j * 16]) = rb[j];
    }
    __syncthreads();

    f32x4 acc[4][4] = {};
    for (int t = 0; t < 12; ++t) {
        if (t < 11) {   // issue next-tile global loads; latency hides under compute
            const int off = (t + 1) * 64;
            #pragma unroll
            for (int j = 0; j < 4; ++j) {
                ra[j] = *(const bf16x8*)(aptr + off + j * 16);
                rb[j] = *(const bf16x8*)(bptr + off + j * 16);
            }
        }
        #pragma unroll
        for (int kk = 0; kk < 2; ++kk) {
            bf16x8 af[4], bfv[4];
            #pragma unroll
            for (int mf = 0; mf < 4; ++mf)
                af[mf] = *(const bf16x8*)(&As[(wr * 64 + mf * 16 + lm) * 72 + kk * 32 + lg * 8]);
            #pragma unroll
            for (int ct = 0; ct < 4; ++ct)
                bfv[ct] = *(const bf16x8*)(&Bs[(wc * 64 + ct * 16 + lm) * 72 + kk * 32 + lg * 8]);
            #pragma unroll
            for (int mf = 0; mf < 4; ++mf)
                #pragma unroll
                for (int ct = 0; ct < 4; ++ct)
                    acc[mf][ct] = MFMA16(af[mf], bfv[ct], acc[mf][ct]);
        }
        if (t < 11) {
            __syncthreads();   // all waves done reading As/Bs
            #pragma unroll
            for (int j = 0; j < 4; ++j) {
                *(bf16x8*)(&As[sr * 72 + scb + j * 16]) = ra[j];
                *(bf16x8*)(&Bs[sr * 72 + scb + j * 16]) = rb[j];
            }
            __syncthreads();
        }
    }

    const int b  = m0 >> 11;
    const int s0 = m0 & 2047;

    if (kind == 2) {  // V: write TRANSPOSED [b][kv][d][s]
        bf16* base = vto + (size_t)(b * 4 + head) * 64 * 2048;
        #pragma unroll
        for (int mf = 0; mf < 4; ++mf)
            #pragma unroll
            for (int r = 0; r < 4; ++r) {
                const int s = s0 + wr * 64 + mf * 16 + lg * 4 + r;
                #pragma unroll
                for (int ct = 0; ct < 4; ++ct)
                    base[(size_t)(ct * 16 + lm) * 2048 + s] = __float2bfloat16(acc[mf][ct][r]);
            }
        return;
    }

    const float* ln = (kind == 0) ? qln : kln;
    float lw[4];
    #pragma unroll
    for (int ct = 0; ct < 4; ++ct) lw[ct] = ln[ct * 16 + lm];

    bf16* base = (kind == 0) ? qo + ((size_t)(b * 12 + head) * 2048 + s0) * 64
                             : ko + ((size_t)(b * 4  + head) * 2048 + s0) * 64;
    #pragma unroll
    for (int mf = 0; mf < 4; ++mf)
        #pragma unroll
        for (int r = 0; r < 4; ++r) {
            float n0 = acc[mf][0][r], n1 = acc[mf][1][r], n2 = acc[mf][2][r], n3 = acc[mf][3][r];
            float ss = n0 * n0 + n1 * n1 + n2 * n2 + n3 * n3;
            ss += __shfl_xor(ss, 1);
            ss += __shfl_xor(ss, 2);
            ss += __shfl_xor(ss, 4);
            ss += __shfl_xor(ss, 8);
            float rms = rsqrtf(ss * (1.0f / 64.0f) + 1e-6f);
            n0 *= rms * lw[0]; n1 *= rms * lw[1]; n2 *= rms * lw[2]; n3 *= rms * lw[3];
            const int row = wr * 64 + mf * 16 + lg * 4 + r;
            const float2* tp = tab + (size_t)(s0 + row) * 32;
            float2 t0 = tp[lm], t1 = tp[lm + 16];
            bf16* dst = base + (size_t)row * 64;
            dst[lm]      = __float2bfloat16(n0 * t0.x - n2 * t0.y);
            dst[lm + 16] = __float2bfloat16(n1 * t1.x - n3 * t1.y);
            dst[lm + 32] = __float2bfloat16(n2 * t0.x + n0 * t0.y);
            dst[lm + 48] = __float2bfloat16(n3 * t1.x + n1 * t1.y);
        }
}

// ================= Kernel 2: MFMA sliding-window attention ======================
// Staged K/V (single buffer + reg prefetch), exp2 softmax. 4 waves, wave = 16 q-rows.
__global__ __launch_bounds__(256) void k_attn(
    const bf16* __restrict__ qi, const bf16* __restrict__ ki,
    const bf16* __restrict__ vti, bf16* __restrict__ ao)
{
    __shared__ bf16 Ks[64 * 72];   // [key][d]
    __shared__ bf16 Vs[64 * 72];   // [d][key]
    __shared__ bf16 Ps[64 * 72];   // per-wave-private rows
    const int tid = threadIdx.x;
    const int w = tid >> 6, l = tid & 63;
    const int lm = l & 15, lg = l >> 4;
    const int qb = blockIdx.x, h = blockIdx.y, b = blockIdx.z;
    const int kv = h / 3;
    const int q0 = qb * 64;
    const float SCL2 = 0.18033688011117042f;   // 0.125 * log2(e)

    const bf16* qbase = qi + ((size_t)((b * 12 + h) * 2048 + q0 + w * 16 + lm)) * 64 + lg * 8;
    bf16x8 qf0 = *(const bf16x8*)(qbase);
    bf16x8 qf1 = *(const bf16x8*)(qbase + 32);

    f32x4 oacc[4] = {};
    float m_[4], l_[4];
    #pragma unroll
    for (int r = 0; r < 4; ++r) { m_[r] = -INFINITY; l_[r] = 0.f; }

    const int sr = tid >> 2, sc = (tid & 3) * 16;
    const bf16* kgb = ki  + (size_t)(b * 4 + kv) * 2048 * 64;
    const bf16* vgb = vti + (size_t)(b * 4 + kv) * 64 * 2048;

    const int kb_lo = (qb > 6) ? (qb - 6) : 0;
    {
        const bf16* kp = kgb + (size_t)(kb_lo * 64 + sr) * 64 + sc;
        const bf16* vp = vgb + (size_t)sr * 2048 + kb_lo * 64 + sc;
        *(bf16x8*)(&Ks[sr * 72 + sc])     = *(const bf16x8*)(kp);
        *(bf16x8*)(&Ks[sr * 72 + sc + 8]) = *(const bf16x8*)(kp + 8);
        *(bf16x8*)(&Vs[sr * 72 + sc])     = *(const bf16x8*)(vp);
        *(bf16x8*)(&Vs[sr * 72 + sc + 8]) = *(const bf16x8*)(vp + 8);
    }
    __syncthreads();

    for (int kb = kb_lo; kb <= qb; ++kb) {
        const int k0 = kb * 64;

        bf16x8 rk0, rk1, rv0, rv1;
        if (kb < qb) {   // prefetch next K/V tile into registers
            const bf16* kp = kgb + (size_t)(k0 + 64 + sr) * 64 + sc;
            const bf16* vp = vgb + (size_t)sr * 2048 + k0 + 64 + sc;
            rk0 = *(const bf16x8*)(kp);
            rk1 = *(const bf16x8*)(kp + 8);
            rv0 = *(const bf16x8*)(vp);
            rv1 = *(const bf16x8*)(vp + 8);
        }

        f32x4 sacc[4];
        #pragma unroll
        for (int kt = 0; kt < 4; ++kt) {
            bf16x8 kf0 = *(const bf16x8*)(&Ks[(kt * 16 + lm) * 72 + lg * 8]);
            bf16x8 kf1 = *(const bf16x8*)(&Ks[(kt * 16 + lm) * 72 + 32 + lg * 8]);
            f32x4 z = {0.f, 0.f, 0.f, 0.f};
            z = MFMA16(qf0, kf0, z);
            sacc[kt] = MFMA16(qf1, kf1, z);
        }

        float pmax[4] = {-INFINITY, -INFINITY, -INFINITY, -INFINITY};
        #pragma unroll
        for (int kt = 0; kt < 4; ++kt)
            #pragma unroll
            for (int r = 0; r < 4; ++r) {
                int kgl = k0 + kt * 16 + lm;
                int qgl = q0 + w * 16 + lg * 4 + r;
                bool ok = (kgl <= qgl) && (kgl > qgl - 384);
                float s = ok ? sacc[kt][r] * SCL2 : -INFINITY;
                sacc[kt][r] = s;
                pmax[r] = fmaxf(pmax[r], s);
            }
        #pragma unroll
        for (int r = 0; r < 4; ++r) {
            float t = pmax[r];
            t = fmaxf(t, __shfl_xor(t, 1));
            t = fmaxf(t, __shfl_xor(t, 2));
            t = fmaxf(t, __shfl_xor(t, 4));
            t = fmaxf(t, __shfl_xor(t, 8));
            pmax[r] = t;
        }

        #pragma unroll
        for (int r = 0; r < 4; ++r) {
            float mnew = fmaxf(m_[r], pmax[r]);
            float scale, rs = 0.f, pv[4];
            if (mnew > -INFINITY) {
                scale = exp2f(m_[r] - mnew);
                #pragma unroll
                for (int kt = 0; kt < 4; ++kt) { pv[kt] = exp2f(sacc[kt][r] - mnew); rs += pv[kt]; }
            } else {
                scale = 1.f;
                #pragma unroll
                for (int kt = 0; kt < 4; ++kt) pv[kt] = 0.f;
            }
            m_[r] = mnew;
            rs += __shfl_xor(rs, 1);
            rs += __shfl_xor(rs, 2);
            rs += __shfl_xor(rs, 4);
            rs += __shfl_xor(rs, 8);
            l_[r] = l_[r] * scale + rs;
            #pragma unroll
            for (int dt = 0; dt < 4; ++dt) oacc[dt][r] *= scale;
            #pragma unroll
            for (int kt = 0; kt < 4; ++kt)
                Ps[(w * 16 + lg * 4 + r) * 72 + kt * 16 + lm] = __float2bfloat16(pv[kt]);
        }

        bf16x8 pf0 = *(const bf16x8*)(&Ps[(w * 16 + lm) * 72 + lg * 8]);
        bf16x8 pf1 = *(const bf16x8*)(&Ps[(w * 16 + lm) * 72 + 32 + lg * 8]);
        #pragma unroll
        for (int dt = 0; dt < 4; ++dt) {
            bf16x8 vf0 = *(const bf16x8*)(&Vs[(dt * 16 + lm) * 72 + lg * 8]);
            bf16x8 vf1 = *(const bf16x8*)(&Vs[(dt * 16 + lm) * 72 + 32 + lg * 8]);
            oacc[dt] = MFMA16(pf0, vf0, oacc[dt]);
            oacc[dt] = MFMA16(pf1, vf1, oacc[dt]);
        }

        if (kb < qb) {
            __syncthreads();   // all waves done reading Ks/Vs
            *(bf16x8*)(&Ks[sr * 72 + sc])     = rk0;
            *(bf16x8*)(&Ks[sr * 72 + sc + 8]) = rk1;
            *(bf16x8*)(&Vs[sr * 72 + sc])     = rv0;
            *(bf16x8*)(&Vs[sr * 72 + sc + 8]) = rv1;
            __syncthreads();
        }
    }

    #pragma unroll
    for (int r = 0; r < 4; ++r) {
        float inv = 1.f / l_[r];
        bf16* dst = ao + ((size_t)(b * 2048 + q0 + w * 16 + lg * 4 + r)) * 768 + h * 64;
        #pragma unroll
        for (int dt = 0; dt < 4; ++dt)
            dst[dt * 16 + lm] = __float2bfloat16(oacc[dt][r] * inv);
    }
}

// ================= Kernel 3: LDS-free MFMA output projection ======================
// grid (32 m, 6 n), 4 waves 2x2; operands straight from L1/L2; zero barriers.
__global__ __launch_bounds__(256) void k_oproj(
    const bf16* __restrict__ A, const bf16* __restrict__ W, float* __restrict__ out)
{
    const int tid = threadIdx.x;
    const int w = tid >> 6, l = tid & 63;
    const int lm = l & 15, lg = l >> 4;
    const int wr = w >> 1, wc = w & 1;
    const int m0 = blockIdx.x * 128, n0 = blockIdx.y * 128;

    const bf16* arow[4];
    const bf16* brow[4];
    #pragma unroll
    for (int i = 0; i < 4; ++i) {
        arow[i] = A + (size_t)(m0 + wr * 64 + i * 16 + lm) * 768 + lg * 8;
        brow[i] = W + (size_t)(n0 + wc * 64 + i * 16 + lm) * 768 + lg * 8;
    }

    f32x4 acc[4][4] = {};
    for (int t = 0; t < 12; ++t) {
        #pragma unroll
        for (int kk = 0; kk < 2; ++kk) {
            const int off = t * 64 + kk * 32;
            bf16x8 af[4], bfv[4];
            #pragma unroll
            for (int mf = 0; mf < 4; ++mf) af[mf]  = *(const bf16x8*)(arow[mf] + off);
            #pragma unroll
            for (int ct = 0; ct < 4; ++ct) bfv[ct] = *(const bf16x8*)(brow[ct] + off);
            #pragma unroll
            for (int mf = 0; mf < 4; ++mf)
                #pragma unroll
                for (int ct = 0; ct < 4; ++ct)
                    acc[mf][ct] = MFMA16(af[mf], bfv[ct], acc[mf][ct]);
        }
    }

    #pragma unroll
    for (int mf = 0; mf < 4; ++mf)
        #pragma unroll
        for (int r = 0; r < 4; ++r) {
            float* dst = out + (size_t)(m0 + wr * 64 + mf * 16 + lg * 4 + r) * 768 + n0 + wc * 64;
            #pragma unroll
            for (int ct = 0; ct < 4; ++ct)
                dst[ct * 16 + lm] = acc[mf][ct][r];
        }
}

extern "C" void kernel_launch(void* const* d_in, const int* in_sizes, int n_in,
                              void* d_out, int out_size, void* d_ws, size_t ws_size,
                              hipStream_t stream) {
    const float* hs  = (const float*)d_in[0];
    const float* qw  = (const float*)d_in[1];
    const float* kw  = (const float*)d_in[2];
    const float* vw  = (const float*)d_in[3];
    const float* ow  = (const float*)d_in[4];
    const float* qln = (const float*)d_in[5];
    const float* kln = (const float*)d_in[6];
    float* out = (float*)d_out;

    float2* tab  = (float2*)d_ws;
    bf16*   q_ws = (bf16*)(tab + 65536);
    bf16*   k_ws = q_ws + 3145728;
    bf16*   vt_ws= k_ws + 1048576;
    bf16*   x_ws = vt_ws + 1048576;    // hsb during k_qkv, attn output after
    bf16*   qwb  = x_ws + 3145728;
    bf16*   kwb  = qwb + 589824;
    bf16*   vwb  = kwb + 196608;
    bf16*   owb  = vwb + 196608;

    k_prep<<<dim3(4864), 256, 0, stream>>>(hs, qw, kw, vw, ow, x_ws, qwb, kwb, vwb, owb, tab);
    k_qkv<<<dim3(32, 10, 1), 256, 0, stream>>>(x_ws, qwb, kwb, vwb, qln, kln, tab, q_ws, k_ws, vt_ws);
    k_attn<<<dim3(32, 12, 2), 256, 0, stream>>>(q_ws, k_ws, vt_ws, x_ws);
    k_oproj<<<dim3(32, 6, 1), 256, 0, stream>>>(x_ws, owb, out);
}

// Round 10
// 81.090 us; speedup vs baseline: 1.2548x; 1.0669x over previous
//
#include <hip/hip_runtime.h>
#include <hip/hip_bf16.h>

typedef __hip_bfloat16 bf16;
typedef __attribute__((ext_vector_type(8))) short bf16x8;   // 8 bf16 = 4 VGPR
typedef __attribute__((ext_vector_type(4))) float f32x4;

#define MFMA16(a, b, c) __builtin_amdgcn_mfma_f32_16x16x32_bf16((a), (b), (c), 0, 0, 0)

// ---- constants ----
// B=2, S=2048, D=768, HD=64, NH=12, NKV=4, GROUPS=3, WINDOW=384, theta=1e4, eps=1e-6
// I/O fp32; bf16 intermediates in ws; V stored transposed [b][kv][d][s].
// R9 lesson: reg-staged LDS is the bottleneck mechanism (m151: 646 vs 874 TF).
// This round: global_load_lds(16B) + linear LDS + m97 2-barrier structure everywhere.

// async global->LDS, 16B per lane. LDS dest is wave-uniform base; HW adds lane*16.
__device__ __forceinline__ void gload16(const bf16* g, bf16* lds) {
    __builtin_amdgcn_global_load_lds(
        (const __attribute__((address_space(1))) void*)g,
        (__attribute__((address_space(3))) void*)lds, 16, 0, 0);
}

__device__ __forceinline__ void st4bf(bf16* p, float4 v) {
    bf16 t[4];
    t[0] = __float2bfloat16(v.x); t[1] = __float2bfloat16(v.y);
    t[2] = __float2bfloat16(v.z); t[3] = __float2bfloat16(v.w);
    *reinterpret_cast<uint2*>(p) = *reinterpret_cast<const uint2*>(t);
}

// ============ Kernel 0: fp32->bf16 conversion of hs + weights, and RoPE table ======
__global__ __launch_bounds__(256) void k_prep(
    const float* __restrict__ hs, const float* __restrict__ qw,
    const float* __restrict__ kw, const float* __restrict__ vw,
    const float* __restrict__ ow,
    bf16* __restrict__ hsb, bf16* __restrict__ qwb, bf16* __restrict__ kwb,
    bf16* __restrict__ vwb, bf16* __restrict__ owb, float2* __restrict__ tab)
{
    const int bid = blockIdx.x, tid = threadIdx.x;
    const float* src; bf16* dst; int rel;
    if (bid < 3072)      { src = hs; dst = hsb; rel = bid; }
    else if (bid < 3648) { src = qw; dst = qwb; rel = bid - 3072; }
    else if (bid < 3840) { src = kw; dst = kwb; rel = bid - 3648; }
    else if (bid < 4032) { src = vw; dst = vwb; rel = bid - 3840; }
    else if (bid < 4608) { src = ow; dst = owb; rel = bid - 4032; }
    else {
        int i = (bid - 4608) * 256 + tid;          // 65536 entries
        int f = i & 31;
        float ang = (float)(i >> 5) * expf(-(float)f * 0.28782313662425572f);  // ln(1e4)/32
        float sn, cs; sincosf(ang, &sn, &cs);
        tab[i] = make_float2(cs, sn);
        return;
    }
    int i = (rel * 256 + tid) * 4;
    float4 v = *reinterpret_cast<const float4*>(src + i);
    st4bf(dst + i, v);
}

// ================= Kernel 1: MFMA QKV GEMM + RMSNorm + RoPE =================
// 128x128 block, 4 waves 2x2 (wave sub-tile 64x64), linear LDS + global_load_lds.
// grid (32 m-tiles, 10 n-blocks): nblk 0-5 q (head 2nblk+wc), 6-7 k, 8-9 v.
__global__ __launch_bounds__(256) void k_qkv(
    const bf16* __restrict__ hsb, const bf16* __restrict__ qwb,
    const bf16* __restrict__ kwb, const bf16* __restrict__ vwb,
    const float* __restrict__ qln, const float* __restrict__ kln,
    const float2* __restrict__ tab,
    bf16* __restrict__ qo, bf16* __restrict__ ko, bf16* __restrict__ vto)
{
    __shared__ bf16 As[128 * 64];   // [row][k], linear
    __shared__ bf16 Bs[128 * 64];
    const int tid = threadIdx.x;
    const int w = tid >> 6, l = tid & 63;
    const int lm = l & 15, lg = l >> 4;
    const int wr = w >> 1, wc = w & 1;
    const int lr8 = l >> 3, lc8 = (l & 7) * 8;   // staging lane -> (row-in-8, col)
    const int m0 = blockIdx.x * 128;
    const int nblk = blockIdx.y;

    const bf16* wsrc; int kind, head;
    if (nblk < 6)      { wsrc = qwb + (size_t)nblk * 128 * 768;       kind = 0; head = nblk * 2 + wc; }
    else if (nblk < 8) { wsrc = kwb + (size_t)(nblk - 6) * 128 * 768; kind = 1; head = (nblk - 6) * 2 + wc; }
    else               { wsrc = vwb + (size_t)(nblk - 8) * 128 * 768; kind = 2; head = (nblk - 8) * 2 + wc; }

    f32x4 acc[4][4] = {};
    for (int t = 0; t < 12; ++t) {
        const int k0 = t * 64;
        if (t) __syncthreads();     // all waves done reading As/Bs
        #pragma unroll
        for (int q = 0; q < 4; ++q) {   // wave w stages rows [w*32, w*32+32)
            const int rbase = w * 32 + q * 8;
            gload16(hsb  + (size_t)(m0 + rbase + lr8) * 768 + k0 + lc8, &As[rbase * 64]);
            gload16(wsrc + (size_t)(rbase + lr8) * 768 + k0 + lc8,      &Bs[rbase * 64]);
        }
        __syncthreads();            // vmcnt drained by barrier semantics -> data landed
        #pragma unroll
        for (int kk = 0; kk < 2; ++kk) {
            bf16x8 af[4], bfv[4];
            #pragma unroll
            for (int mf = 0; mf < 4; ++mf)
                af[mf] = *(const bf16x8*)(&As[(wr * 64 + mf * 16 + lm) * 64 + kk * 32 + lg * 8]);
            #pragma unroll
            for (int ct = 0; ct < 4; ++ct)
                bfv[ct] = *(const bf16x8*)(&Bs[(wc * 64 + ct * 16 + lm) * 64 + kk * 32 + lg * 8]);
            #pragma unroll
            for (int mf = 0; mf < 4; ++mf)
                #pragma unroll
                for (int ct = 0; ct < 4; ++ct)
                    acc[mf][ct] = MFMA16(af[mf], bfv[ct], acc[mf][ct]);
        }
    }

    const int b  = m0 >> 11;
    const int s0 = m0 & 2047;

    if (kind == 2) {  // V: write TRANSPOSED [b][kv][d][s]
        bf16* base = vto + (size_t)(b * 4 + head) * 64 * 2048;
        #pragma unroll
        for (int mf = 0; mf < 4; ++mf)
            #pragma unroll
            for (int r = 0; r < 4; ++r) {
                const int s = s0 + wr * 64 + mf * 16 + lg * 4 + r;
                #pragma unroll
                for (int ct = 0; ct < 4; ++ct)
                    base[(size_t)(ct * 16 + lm) * 2048 + s] = __float2bfloat16(acc[mf][ct][r]);
            }
        return;
    }

    const float* ln = (kind == 0) ? qln : kln;
    float lw[4];
    #pragma unroll
    for (int ct = 0; ct < 4; ++ct) lw[ct] = ln[ct * 16 + lm];

    bf16* base = (kind == 0) ? qo + ((size_t)(b * 12 + head) * 2048 + s0) * 64
                             : ko + ((size_t)(b * 4  + head) * 2048 + s0) * 64;
    #pragma unroll
    for (int mf = 0; mf < 4; ++mf)
        #pragma unroll
        for (int r = 0; r < 4; ++r) {
            float n0 = acc[mf][0][r], n1 = acc[mf][1][r], n2 = acc[mf][2][r], n3 = acc[mf][3][r];
            float ss = n0 * n0 + n1 * n1 + n2 * n2 + n3 * n3;
            ss += __shfl_xor(ss, 1);
            ss += __shfl_xor(ss, 2);
            ss += __shfl_xor(ss, 4);
            ss += __shfl_xor(ss, 8);
            float rms = rsqrtf(ss * (1.0f / 64.0f) + 1e-6f);
            n0 *= rms * lw[0]; n1 *= rms * lw[1]; n2 *= rms * lw[2]; n3 *= rms * lw[3];
            const int row = wr * 64 + mf * 16 + lg * 4 + r;
            const float2* tp = tab + (size_t)(s0 + row) * 32;
            float2 t0 = tp[lm], t1 = tp[lm + 16];
            bf16* dst = base + (size_t)row * 64;
            dst[lm]      = __float2bfloat16(n0 * t0.x - n2 * t0.y);
            dst[lm + 16] = __float2bfloat16(n1 * t1.x - n3 * t1.y);
            dst[lm + 32] = __float2bfloat16(n2 * t0.x + n0 * t0.y);
            dst[lm + 48] = __float2bfloat16(n3 * t1.x + n1 * t1.y);
        }
}

// ================= Kernel 2: MFMA sliding-window attention ======================
// K/V staged via global_load_lds into linear [64][64] tiles; exp2 softmax.
__global__ __launch_bounds__(256) void k_attn(
    const bf16* __restrict__ qi, const bf16* __restrict__ ki,
    const bf16* __restrict__ vti, bf16* __restrict__ ao)
{
    __shared__ bf16 Ks[64 * 64];   // [key][d], linear
    __shared__ bf16 Vs[64 * 64];   // [d][key], linear
    __shared__ bf16 Ps[64 * 72];   // per-wave-private rows, padded
    const int tid = threadIdx.x;
    const int w = tid >> 6, l = tid & 63;
    const int lm = l & 15, lg = l >> 4;
    const int lr8 = l >> 3, lc8 = (l & 7) * 8;
    const int qb = blockIdx.x, h = blockIdx.y, b = blockIdx.z;
    const int kv = h / 3;
    const int q0 = qb * 64;
    const float SCL2 = 0.18033688011117042f;   // 0.125 * log2(e)

    const bf16* qbase = qi + ((size_t)((b * 12 + h) * 2048 + q0 + w * 16 + lm)) * 64 + lg * 8;
    bf16x8 qf0 = *(const bf16x8*)(qbase);
    bf16x8 qf1 = *(const bf16x8*)(qbase + 32);

    f32x4 oacc[4] = {};
    float m_[4], l_[4];
    #pragma unroll
    for (int r = 0; r < 4; ++r) { m_[r] = -INFINITY; l_[r] = 0.f; }

    const bf16* kgb = ki  + (size_t)(b * 4 + kv) * 2048 * 64;
    const bf16* vgb = vti + (size_t)(b * 4 + kv) * 64 * 2048;

    const int kb_lo = (qb > 6) ? (qb - 6) : 0;
    for (int kb = kb_lo; kb <= qb; ++kb) {
        const int k0 = kb * 64;

        if (kb > kb_lo) __syncthreads();   // all waves done reading Ks/Vs
        #pragma unroll
        for (int q = 0; q < 2; ++q) {      // wave w stages rows [w*16, w*16+16)
            const int rbase = w * 16 + q * 8;
            gload16(kgb + (size_t)(k0 + rbase + lr8) * 64 + lc8,   &Ks[rbase * 64]);
            gload16(vgb + (size_t)(rbase + lr8) * 2048 + k0 + lc8, &Vs[rbase * 64]);
        }
        __syncthreads();                   // data landed

        f32x4 sacc[4];
        #pragma unroll
        for (int kt = 0; kt < 4; ++kt) {
            bf16x8 kf0 = *(const bf16x8*)(&Ks[(kt * 16 + lm) * 64 + lg * 8]);
            bf16x8 kf1 = *(const bf16x8*)(&Ks[(kt * 16 + lm) * 64 + 32 + lg * 8]);
            f32x4 z = {0.f, 0.f, 0.f, 0.f};
            z = MFMA16(qf0, kf0, z);
            sacc[kt] = MFMA16(qf1, kf1, z);
        }

        float pmax[4] = {-INFINITY, -INFINITY, -INFINITY, -INFINITY};
        #pragma unroll
        for (int kt = 0; kt < 4; ++kt)
            #pragma unroll
            for (int r = 0; r < 4; ++r) {
                int kgl = k0 + kt * 16 + lm;
                int qgl = q0 + w * 16 + lg * 4 + r;
                bool ok = (kgl <= qgl) && (kgl > qgl - 384);
                float s = ok ? sacc[kt][r] * SCL2 : -INFINITY;
                sacc[kt][r] = s;
                pmax[r] = fmaxf(pmax[r], s);
            }
        #pragma unroll
        for (int r = 0; r < 4; ++r) {
            float t = pmax[r];
            t = fmaxf(t, __shfl_xor(t, 1));
            t = fmaxf(t, __shfl_xor(t, 2));
            t = fmaxf(t, __shfl_xor(t, 4));
            t = fmaxf(t, __shfl_xor(t, 8));
            pmax[r] = t;
        }

        #pragma unroll
        for (int r = 0; r < 4; ++r) {
            float mnew = fmaxf(m_[r], pmax[r]);
            float scale, rs = 0.f, pv[4];
            if (mnew > -INFINITY) {
                scale = exp2f(m_[r] - mnew);
                #pragma unroll
                for (int kt = 0; kt < 4; ++kt) { pv[kt] = exp2f(sacc[kt][r] - mnew); rs += pv[kt]; }
            } else {
                scale = 1.f;
                #pragma unroll
                for (int kt = 0; kt < 4; ++kt) pv[kt] = 0.f;
            }
            m_[r] = mnew;
            rs += __shfl_xor(rs, 1);
            rs += __shfl_xor(rs, 2);
            rs += __shfl_xor(rs, 4);
            rs += __shfl_xor(rs, 8);
            l_[r] = l_[r] * scale + rs;
            #pragma unroll
            for (int dt = 0; dt < 4; ++dt) oacc[dt][r] *= scale;
            #pragma unroll
            for (int kt = 0; kt < 4; ++kt)
                Ps[(w * 16 + lg * 4 + r) * 72 + kt * 16 + lm] = __float2bfloat16(pv[kt]);
        }

        bf16x8 pf0 = *(const bf16x8*)(&Ps[(w * 16 + lm) * 72 + lg * 8]);
        bf16x8 pf1 = *(const bf16x8*)(&Ps[(w * 16 + lm) * 72 + 32 + lg * 8]);
        #pragma unroll
        for (int dt = 0; dt < 4; ++dt) {
            bf16x8 vf0 = *(const bf16x8*)(&Vs[(dt * 16 + lm) * 64 + lg * 8]);
            bf16x8 vf1 = *(const bf16x8*)(&Vs[(dt * 16 + lm) * 64 + 32 + lg * 8]);
            oacc[dt] = MFMA16(pf0, vf0, oacc[dt]);
            oacc[dt] = MFMA16(pf1, vf1, oacc[dt]);
        }
    }

    #pragma unroll
    for (int r = 0; r < 4; ++r) {
        float inv = 1.f / l_[r];
        bf16* dst = ao + ((size_t)(b * 2048 + q0 + w * 16 + lg * 4 + r)) * 768 + h * 64;
        #pragma unroll
        for (int dt = 0; dt < 4; ++dt)
            dst[dt * 16 + lm] = __float2bfloat16(oacc[dt][r] * inv);
    }
}

// ================= Kernel 3: MFMA output projection (m97 structure) ==============
// grid (32 m, 6 n), 128x128, 4 waves 2x2, global_load_lds staging, fp32 out.
__global__ __launch_bounds__(256) void k_oproj(
    const bf16* __restrict__ A, const bf16* __restrict__ W, float* __restrict__ out)
{
    __shared__ bf16 As[128 * 64];
    __shared__ bf16 Bs[128 * 64];
    const int tid = threadIdx.x;
    const int w = tid >> 6, l = tid & 63;
    const int lm = l & 15, lg = l >> 4;
    const int wr = w >> 1, wc = w & 1;
    const int lr8 = l >> 3, lc8 = (l & 7) * 8;
    const int m0 = blockIdx.x * 128, n0 = blockIdx.y * 128;

    f32x4 acc[4][4] = {};
    for (int t = 0; t < 12; ++t) {
        const int k0 = t * 64;
        if (t) __syncthreads();
        #pragma unroll
        for (int q = 0; q < 4; ++q) {
            const int rbase = w * 32 + q * 8;
            gload16(A + (size_t)(m0 + rbase + lr8) * 768 + k0 + lc8, &As[rbase * 64]);
            gload16(W + (size_t)(n0 + rbase + lr8) * 768 + k0 + lc8, &Bs[rbase * 64]);
        }
        __syncthreads();
        #pragma unroll
        for (int kk = 0; kk < 2; ++kk) {
            bf16x8 af[4], bfv[4];
            #pragma unroll
            for (int mf = 0; mf < 4; ++mf)
                af[mf] = *(const bf16x8*)(&As[(wr * 64 + mf * 16 + lm) * 64 + kk * 32 + lg * 8]);
            #pragma unroll
            for (int ct = 0; ct < 4; ++ct)
                bfv[ct] = *(const bf16x8*)(&Bs[(wc * 64 + ct * 16 + lm) * 64 + kk * 32 + lg * 8]);
            #pragma unroll
            for (int mf = 0; mf < 4; ++mf)
                #pragma unroll
                for (int ct = 0; ct < 4; ++ct)
                    acc[mf][ct] = MFMA16(af[mf], bfv[ct], acc[mf][ct]);
        }
    }

    #pragma unroll
    for (int mf = 0; mf < 4; ++mf)
        #pragma unroll
        for (int r = 0; r < 4; ++r) {
            float* dst = out + (size_t)(m0 + wr * 64 + mf * 16 + lg * 4 + r) * 768 + n0 + wc * 64;
            #pragma unroll
            for (int ct = 0; ct < 4; ++ct)
                dst[ct * 16 + lm] = acc[mf][ct][r];
        }
}

extern "C" void kernel_launch(void* const* d_in, const int* in_sizes, int n_in,
                              void* d_out, int out_size, void* d_ws, size_t ws_size,
                              hipStream_t stream) {
    const float* hs  = (const float*)d_in[0];
    const float* qw  = (const float*)d_in[1];
    const float* kw  = (const float*)d_in[2];
    const float* vw  = (const float*)d_in[3];
    const float* ow  = (const float*)d_in[4];
    const float* qln = (const float*)d_in[5];
    const float* kln = (const float*)d_in[6];
    float* out = (float*)d_out;

    float2* tab  = (float2*)d_ws;
    bf16*   q_ws = (bf16*)(tab + 65536);
    bf16*   k_ws = q_ws + 3145728;
    bf16*   vt_ws= k_ws + 1048576;
    bf16*   x_ws = vt_ws + 1048576;    // hsb during k_qkv, attn output after
    bf16*   qwb  = x_ws + 3145728;
    bf16*   kwb  = qwb + 589824;
    bf16*   vwb  = kwb + 196608;
    bf16*   owb  = vwb + 196608;

    k_prep<<<dim3(4864), 256, 0, stream>>>(hs, qw, kw, vw, ow, x_ws, qwb, kwb, vwb, owb, tab);
    k_qkv<<<dim3(32, 10, 1), 256, 0, stream>>>(x_ws, qwb, kwb, vwb, qln, kln, tab, q_ws, k_ws, vt_ws);
    k_attn<<<dim3(32, 12, 2), 256, 0, stream>>>(q_ws, k_ws, vt_ws, x_ws);
    k_oproj<<<dim3(32, 6, 1), 256, 0, stream>>>(x_ws, owb, out);
}

// Round 11
// 69.488 us; speedup vs baseline: 1.4643x; 1.1670x over previous
//
#include <hip/hip_runtime.h>
#include <hip/hip_bf16.h>

typedef __hip_bfloat16 bf16;
typedef __attribute__((ext_vector_type(8))) short bf16x8;   // 8 bf16 = 4 VGPR
typedef __attribute__((ext_vector_type(4))) float f32x4;

#define MFMA16(a, b, c) __builtin_amdgcn_mfma_f32_16x16x32_bf16((a), (b), (c), 0, 0, 0)

// ---- constants ----
// B=2, S=2048, D=768, HD=64, NH=12, NKV=4, GROUPS=3, WINDOW=384, theta=1e4, eps=1e-6
// I/O fp32; bf16 intermediates in ws; V stored transposed [b][kv][d][s].
// R10 ledger: best = R5 (dbuf + reg-prefetch, 2 barriers/iter) = 73.7us.
// This round: SINGLE barrier/iter dbuf (write->bar->issue-next->compute) + uniform-branch
// mask skip on interior attention tiles. Everything else identical to R5.

__device__ __forceinline__ void st4bf(bf16* p, float4 v) {
    bf16 t[4];
    t[0] = __float2bfloat16(v.x); t[1] = __float2bfloat16(v.y);
    t[2] = __float2bfloat16(v.z); t[3] = __float2bfloat16(v.w);
    *reinterpret_cast<uint2*>(p) = *reinterpret_cast<const uint2*>(t);
}

// ============ Kernel 0: fp32->bf16 conversion of hs + weights, and RoPE table ======
__global__ __launch_bounds__(256) void k_prep(
    const float* __restrict__ hs, const float* __restrict__ qw,
    const float* __restrict__ kw, const float* __restrict__ vw,
    const float* __restrict__ ow,
    bf16* __restrict__ hsb, bf16* __restrict__ qwb, bf16* __restrict__ kwb,
    bf16* __restrict__ vwb, bf16* __restrict__ owb, float2* __restrict__ tab)
{
    const int bid = blockIdx.x, tid = threadIdx.x;
    const float* src; bf16* dst; int rel;
    if (bid < 3072)      { src = hs; dst = hsb; rel = bid; }
    else if (bid < 3648) { src = qw; dst = qwb; rel = bid - 3072; }
    else if (bid < 3840) { src = kw; dst = kwb; rel = bid - 3648; }
    else if (bid < 4032) { src = vw; dst = vwb; rel = bid - 3840; }
    else if (bid < 4608) { src = ow; dst = owb; rel = bid - 4032; }
    else {
        int i = (bid - 4608) * 256 + tid;          // 65536 entries
        int f = i & 31;
        float ang = (float)(i >> 5) * expf(-(float)f * 0.28782313662425572f);  // ln(1e4)/32
        float sn, cs; sincosf(ang, &sn, &cs);
        tab[i] = make_float2(cs, sn);
        return;
    }
    int i = (rel * 256 + tid) * 4;
    float4 v = *reinterpret_cast<const float4*>(src + i);
    st4bf(dst + i, v);
}

// ================= Kernel 1: MFMA QKV GEMM + RMSNorm + RoPE =================
// 64x64 block, 4 waves (wave = 16 rows), dbuf + reg-prefetch, ONE barrier per K-step.
// grid (64 m-tiles, 20 n-blocks): 0-11 q heads, 12-15 k heads, 16-19 v heads.
__global__ __launch_bounds__(256) void k_qkv(
    const bf16* __restrict__ hsb, const bf16* __restrict__ qwb,
    const bf16* __restrict__ kwb, const bf16* __restrict__ vwb,
    const float* __restrict__ qln, const float* __restrict__ kln,
    const float2* __restrict__ tab,
    bf16* __restrict__ qo, bf16* __restrict__ ko, bf16* __restrict__ vto)
{
    __shared__ bf16 As[2][64 * 72];
    __shared__ bf16 Bs[2][64 * 72];
    const int tid = threadIdx.x;
    const int w = tid >> 6, l = tid & 63;
    const int lm = l & 15, lg = l >> 4;
    const int m0 = blockIdx.x * 64;
    const int nblk = blockIdx.y;

    const bf16* wsrc; int wrow0, kind, head;
    if (nblk < 12)      { wsrc = qwb; wrow0 = nblk * 64;        kind = 0; head = nblk; }
    else if (nblk < 16) { wsrc = kwb; wrow0 = (nblk - 12) * 64; kind = 1; head = nblk - 12; }
    else                { wsrc = vwb; wrow0 = (nblk - 16) * 64; kind = 2; head = nblk - 16; }

    const int sr = tid >> 2, sc = (tid & 3) * 16;
    const bf16* aptr = hsb  + (size_t)(m0 + sr) * 768 + sc;
    const bf16* bptr = wsrc + (size_t)(wrow0 + sr) * 768 + sc;

    // prologue: tile 0 into regs
    bf16x8 ra0 = *(const bf16x8*)(aptr);
    bf16x8 ra1 = *(const bf16x8*)(aptr + 8);
    bf16x8 rb0 = *(const bf16x8*)(bptr);
    bf16x8 rb1 = *(const bf16x8*)(bptr + 8);

    f32x4 acc[4] = {};
    for (int t = 0; t < 12; ++t) {
        const int p = t & 1;
        // write tile t (in regs) to buf p. Safe: all waves passed iter t-1's barrier,
        // which (program order) implies they finished computing iter t-2 from buf p.
        *(bf16x8*)(&As[p][sr * 72 + sc])     = ra0;
        *(bf16x8*)(&As[p][sr * 72 + sc + 8]) = ra1;
        *(bf16x8*)(&Bs[p][sr * 72 + sc])     = rb0;
        *(bf16x8*)(&Bs[p][sr * 72 + sc + 8]) = rb1;
        __syncthreads();
        if (t < 11) {   // issue next-tile loads; latency hides under this tile's compute
            const int off = (t + 1) * 64;
            ra0 = *(const bf16x8*)(aptr + off);
            ra1 = *(const bf16x8*)(aptr + off + 8);
            rb0 = *(const bf16x8*)(bptr + off);
            rb1 = *(const bf16x8*)(bptr + off + 8);
        }
        #pragma unroll
        for (int kk = 0; kk < 2; ++kk) {
            bf16x8 af = *(const bf16x8*)(&As[p][(w * 16 + lm) * 72 + kk * 32 + lg * 8]);
            #pragma unroll
            for (int ct = 0; ct < 4; ++ct) {
                bf16x8 bfr = *(const bf16x8*)(&Bs[p][(ct * 16 + lm) * 72 + kk * 32 + lg * 8]);
                acc[ct] = MFMA16(af, bfr, acc[ct]);
            }
        }
    }

    const int b  = m0 >> 11;
    const int s0 = m0 & 2047;

    if (kind == 2) {  // V: write TRANSPOSED [b][kv][d][s]
        bf16* base = vto + (size_t)(b * 4 + head) * 64 * 2048;
        #pragma unroll
        for (int r = 0; r < 4; ++r) {
            const int s = s0 + w * 16 + lg * 4 + r;
            #pragma unroll
            for (int ct = 0; ct < 4; ++ct)
                base[(size_t)(ct * 16 + lm) * 2048 + s] = __float2bfloat16(acc[ct][r]);
        }
        return;
    }

    const float* ln = (kind == 0) ? qln : kln;
    float lw[4];
    #pragma unroll
    for (int ct = 0; ct < 4; ++ct) lw[ct] = ln[ct * 16 + lm];

    bf16* base = (kind == 0) ? qo + ((size_t)(b * 12 + head) * 2048 + s0) * 64
                             : ko + ((size_t)(b * 4  + head) * 2048 + s0) * 64;
    #pragma unroll
    for (int r = 0; r < 4; ++r) {
        float n0 = acc[0][r], n1 = acc[1][r], n2 = acc[2][r], n3 = acc[3][r];
        float ss = n0 * n0 + n1 * n1 + n2 * n2 + n3 * n3;
        ss += __shfl_xor(ss, 1);
        ss += __shfl_xor(ss, 2);
        ss += __shfl_xor(ss, 4);
        ss += __shfl_xor(ss, 8);
        float rms = rsqrtf(ss * (1.0f / 64.0f) + 1e-6f);
        n0 *= rms * lw[0]; n1 *= rms * lw[1]; n2 *= rms * lw[2]; n3 *= rms * lw[3];
        const int row = w * 16 + lg * 4 + r;
        const float2* tp = tab + (size_t)(s0 + row) * 32;
        float2 t0 = tp[lm], t1 = tp[lm + 16];
        bf16* dst = base + (size_t)row * 64;
        dst[lm]      = __float2bfloat16(n0 * t0.x - n2 * t0.y);
        dst[lm + 16] = __float2bfloat16(n1 * t1.x - n3 * t1.y);
        dst[lm + 32] = __float2bfloat16(n2 * t0.x + n0 * t0.y);
        dst[lm + 48] = __float2bfloat16(n3 * t1.x + n1 * t1.y);
    }
}

// ================= Kernel 2: MFMA sliding-window attention ======================
// dbuf K/V + reg-prefetch, ONE barrier per tile; masks only on diagonal/window-edge
// tiles (uniform branch). exp2 softmax.
__global__ __launch_bounds__(256) void k_attn(
    const bf16* __restrict__ qi, const bf16* __restrict__ ki,
    const bf16* __restrict__ vti, bf16* __restrict__ ao)
{
    __shared__ bf16 Ks[2][64 * 72];   // [key][d]
    __shared__ bf16 Vs[2][64 * 72];   // [d][key]
    __shared__ bf16 Ps[64 * 72];      // per-wave-private rows
    const int tid = threadIdx.x;
    const int w = tid >> 6, l = tid & 63;
    const int lm = l & 15, lg = l >> 4;
    const int qb = blockIdx.x, h = blockIdx.y, b = blockIdx.z;
    const int kv = h / 3;
    const int q0 = qb * 64;
    const float SCL2 = 0.18033688011117042f;   // 0.125 * log2(e)

    const bf16* qbase = qi + ((size_t)((b * 12 + h) * 2048 + q0 + w * 16 + lm)) * 64 + lg * 8;
    bf16x8 qf0 = *(const bf16x8*)(qbase);
    bf16x8 qf1 = *(const bf16x8*)(qbase + 32);

    f32x4 oacc[4] = {};
    float m_[4], l_[4];
    #pragma unroll
    for (int r = 0; r < 4; ++r) { m_[r] = -INFINITY; l_[r] = 0.f; }

    const int sr = tid >> 2, sc = (tid & 3) * 16;
    const bf16* kgb = ki  + (size_t)(b * 4 + kv) * 2048 * 64;
    const bf16* vgb = vti + (size_t)(b * 4 + kv) * 64 * 2048;

    const int kb_lo = (qb > 6) ? (qb - 6) : 0;
    // prologue: tile kb_lo into regs
    bf16x8 rk0, rk1, rv0, rv1;
    {
        const bf16* kp = kgb + (size_t)(kb_lo * 64 + sr) * 64 + sc;
        const bf16* vp = vgb + (size_t)sr * 2048 + kb_lo * 64 + sc;
        rk0 = *(const bf16x8*)(kp);
        rk1 = *(const bf16x8*)(kp + 8);
        rv0 = *(const bf16x8*)(vp);
        rv1 = *(const bf16x8*)(vp + 8);
    }

    for (int kb = kb_lo; kb <= qb; ++kb) {
        const int p = (kb - kb_lo) & 1;
        const int k0 = kb * 64;

        *(bf16x8*)(&Ks[p][sr * 72 + sc])     = rk0;
        *(bf16x8*)(&Ks[p][sr * 72 + sc + 8]) = rk1;
        *(bf16x8*)(&Vs[p][sr * 72 + sc])     = rv0;
        *(bf16x8*)(&Vs[p][sr * 72 + sc + 8]) = rv1;
        __syncthreads();
        if (kb < qb) {   // prefetch next K/V tile into regs
            const bf16* kp = kgb + (size_t)(k0 + 64 + sr) * 64 + sc;
            const bf16* vp = vgb + (size_t)sr * 2048 + k0 + 64 + sc;
            rk0 = *(const bf16x8*)(kp);
            rk1 = *(const bf16x8*)(kp + 8);
            rv0 = *(const bf16x8*)(vp);
            rv1 = *(const bf16x8*)(vp + 8);
        }

        f32x4 sacc[4];
        #pragma unroll
        for (int kt = 0; kt < 4; ++kt) {
            bf16x8 kf0 = *(const bf16x8*)(&Ks[p][(kt * 16 + lm) * 72 + lg * 8]);
            bf16x8 kf1 = *(const bf16x8*)(&Ks[p][(kt * 16 + lm) * 72 + 32 + lg * 8]);
            f32x4 z = {0.f, 0.f, 0.f, 0.f};
            z = MFMA16(qf0, kf0, z);
            sacc[kt] = MFMA16(qf1, kf1, z);
        }

        float pmax[4] = {-INFINITY, -INFINITY, -INFINITY, -INFINITY};
        const bool need_mask = (kb == qb) || (kb == qb - 6);   // wave-uniform
        if (need_mask) {
            #pragma unroll
            for (int kt = 0; kt < 4; ++kt)
                #pragma unroll
                for (int r = 0; r < 4; ++r) {
                    int kgl = k0 + kt * 16 + lm;
                    int qgl = q0 + w * 16 + lg * 4 + r;
                    bool ok = (kgl <= qgl) && (kgl > qgl - 384);
                    float s = ok ? sacc[kt][r] * SCL2 : -INFINITY;
                    sacc[kt][r] = s;
                    pmax[r] = fmaxf(pmax[r], s);
                }
        } else {
            #pragma unroll
            for (int kt = 0; kt < 4; ++kt)
                #pragma unroll
                for (int r = 0; r < 4; ++r) {
                    float s = sacc[kt][r] * SCL2;
                    sacc[kt][r] = s;
                    pmax[r] = fmaxf(pmax[r], s);
                }
        }
        #pragma unroll
        for (int r = 0; r < 4; ++r) {
            float t = pmax[r];
            t = fmaxf(t, __shfl_xor(t, 1));
            t = fmaxf(t, __shfl_xor(t, 2));
            t = fmaxf(t, __shfl_xor(t, 4));
            t = fmaxf(t, __shfl_xor(t, 8));
            pmax[r] = t;
        }

        if (need_mask) {
            #pragma unroll
            for (int r = 0; r < 4; ++r) {
                float mnew = fmaxf(m_[r], pmax[r]);
                float scale, rs = 0.f, pv[4];
                if (mnew > -INFINITY) {   // guard: window-edge tile has a fully-masked row
                    scale = exp2f(m_[r] - mnew);
                    #pragma unroll
                    for (int kt = 0; kt < 4; ++kt) { pv[kt] = exp2f(sacc[kt][r] - mnew); rs += pv[kt]; }
                } else {
                    scale = 1.f;
                    #pragma unroll
                    for (int kt = 0; kt < 4; ++kt) pv[kt] = 0.f;
                }
                m_[r] = mnew;
                rs += __shfl_xor(rs, 1);
                rs += __shfl_xor(rs, 2);
                rs += __shfl_xor(rs, 4);
                rs += __shfl_xor(rs, 8);
                l_[r] = l_[r] * scale + rs;
                #pragma unroll
                for (int dt = 0; dt < 4; ++dt) oacc[dt][r] *= scale;
                #pragma unroll
                for (int kt = 0; kt < 4; ++kt)
                    Ps[(w * 16 + lg * 4 + r) * 72 + kt * 16 + lm] = __float2bfloat16(pv[kt]);
            }
        } else {
            #pragma unroll
            for (int r = 0; r < 4; ++r) {
                float mnew = fmaxf(m_[r], pmax[r]);       // pmax finite; exp2(-inf)=0 ok
                float scale = exp2f(m_[r] - mnew);
                float rs = 0.f, pv[4];
                #pragma unroll
                for (int kt = 0; kt < 4; ++kt) { pv[kt] = exp2f(sacc[kt][r] - mnew); rs += pv[kt]; }
                m_[r] = mnew;
                rs += __shfl_xor(rs, 1);
                rs += __shfl_xor(rs, 2);
                rs += __shfl_xor(rs, 4);
                rs += __shfl_xor(rs, 8);
                l_[r] = l_[r] * scale + rs;
                #pragma unroll
                for (int dt = 0; dt < 4; ++dt) oacc[dt][r] *= scale;
                #pragma unroll
                for (int kt = 0; kt < 4; ++kt)
                    Ps[(w * 16 + lg * 4 + r) * 72 + kt * 16 + lm] = __float2bfloat16(pv[kt]);
            }
        }

        bf16x8 pf0 = *(const bf16x8*)(&Ps[(w * 16 + lm) * 72 + lg * 8]);
        bf16x8 pf1 = *(const bf16x8*)(&Ps[(w * 16 + lm) * 72 + 32 + lg * 8]);
        #pragma unroll
        for (int dt = 0; dt < 4; ++dt) {
            bf16x8 vf0 = *(const bf16x8*)(&Vs[p][(dt * 16 + lm) * 72 + lg * 8]);
            bf16x8 vf1 = *(const bf16x8*)(&Vs[p][(dt * 16 + lm) * 72 + 32 + lg * 8]);
            oacc[dt] = MFMA16(pf0, vf0, oacc[dt]);
            oacc[dt] = MFMA16(pf1, vf1, oacc[dt]);
        }
    }

    #pragma unroll
    for (int r = 0; r < 4; ++r) {
        float inv = 1.f / l_[r];
        bf16* dst = ao + ((size_t)(b * 2048 + q0 + w * 16 + lg * 4 + r)) * 768 + h * 64;
        #pragma unroll
        for (int dt = 0; dt < 4; ++dt)
            dst[dt * 16 + lm] = __float2bfloat16(oacc[dt][r] * inv);
    }
}

// ================= Kernel 3: MFMA output projection ==============================
// 64x64 block, 4 waves, dbuf + reg-prefetch, ONE barrier per K-step. fp32 out.
__global__ __launch_bounds__(256) void k_oproj(
    const bf16* __restrict__ A, const bf16* __restrict__ W, float* __restrict__ out)
{
    __shared__ bf16 As[2][64 * 72];
    __shared__ bf16 Bs[2][64 * 72];
    const int tid = threadIdx.x;
    const int w = tid >> 6, l = tid & 63;
    const int lm = l & 15, lg = l >> 4;
    const int m0 = blockIdx.x * 64, n0 = blockIdx.y * 64;

    const int sr = tid >> 2, sc = (tid & 3) * 16;
    const bf16* aptr = A + (size_t)(m0 + sr) * 768 + sc;
    const bf16* bptr = W + (size_t)(n0 + sr) * 768 + sc;

    bf16x8 ra0 = *(const bf16x8*)(aptr);
    bf16x8 ra1 = *(const bf16x8*)(aptr + 8);
    bf16x8 rb0 = *(const bf16x8*)(bptr);
    bf16x8 rb1 = *(const bf16x8*)(bptr + 8);

    f32x4 acc[4] = {};
    for (int t = 0; t < 12; ++t) {
        const int p = t & 1;
        *(bf16x8*)(&As[p][sr * 72 + sc])     = ra0;
        *(bf16x8*)(&As[p][sr * 72 + sc + 8]) = ra1;
        *(bf16x8*)(&Bs[p][sr * 72 + sc])     = rb0;
        *(bf16x8*)(&Bs[p][sr * 72 + sc + 8]) = rb1;
        __syncthreads();
        if (t < 11) {
            const int off = (t + 1) * 64;
            ra0 = *(const bf16x8*)(aptr + off);
            ra1 = *(const bf16x8*)(aptr + off + 8);
            rb0 = *(const bf16x8*)(bptr + off);
            rb1 = *(const bf16x8*)(bptr + off + 8);
        }
        #pragma unroll
        for (int kk = 0; kk < 2; ++kk) {
            bf16x8 af = *(const bf16x8*)(&As[p][(w * 16 + lm) * 72 + kk * 32 + lg * 8]);
            #pragma unroll
            for (int ct = 0; ct < 4; ++ct) {
                bf16x8 bfr = *(const bf16x8*)(&Bs[p][(ct * 16 + lm) * 72 + kk * 32 + lg * 8]);
                acc[ct] = MFMA16(af, bfr, acc[ct]);
            }
        }
    }

    #pragma unroll
    for (int r = 0; r < 4; ++r) {
        float* dst = out + (size_t)(m0 + w * 16 + lg * 4 + r) * 768 + n0;
        #pragma unroll
        for (int ct = 0; ct < 4; ++ct)
            dst[ct * 16 + lm] = acc[ct][r];
    }
}

extern "C" void kernel_launch(void* const* d_in, const int* in_sizes, int n_in,
                              void* d_out, int out_size, void* d_ws, size_t ws_size,
                              hipStream_t stream) {
    const float* hs  = (const float*)d_in[0];
    const float* qw  = (const float*)d_in[1];
    const float* kw  = (const float*)d_in[2];
    const float* vw  = (const float*)d_in[3];
    const float* ow  = (const float*)d_in[4];
    const float* qln = (const float*)d_in[5];
    const float* kln = (const float*)d_in[6];
    float* out = (float*)d_out;

    float2* tab  = (float2*)d_ws;
    bf16*   q_ws = (bf16*)(tab + 65536);
    bf16*   k_ws = q_ws + 3145728;
    bf16*   vt_ws= k_ws + 1048576;
    bf16*   x_ws = vt_ws + 1048576;    // hsb during k_qkv, attn output after
    bf16*   qwb  = x_ws + 3145728;
    bf16*   kwb  = qwb + 589824;
    bf16*   vwb  = kwb + 196608;
    bf16*   owb  = vwb + 196608;

    k_prep<<<dim3(4864), 256, 0, stream>>>(hs, qw, kw, vw, ow, x_ws, qwb, kwb, vwb, owb, tab);
    k_qkv<<<dim3(64, 20, 1), 256, 0, stream>>>(x_ws, qwb, kwb, vwb, qln, kln, tab, q_ws, k_ws, vt_ws);
    k_attn<<<dim3(32, 12, 2), 256, 0, stream>>>(q_ws, k_ws, vt_ws, x_ws);
    k_oproj<<<dim3(64, 12, 1), 256, 0, stream>>>(x_ws, owb, out);
}